// Round 7
// baseline (915.198 us; speedup 1.0000x reference)
//
#include <hip/hip_runtime.h>
#include <hip/hip_bf16.h>
#include <hip/hip_cooperative_groups.h>

#define DFEAT 128

typedef short bf16x8 __attribute__((ext_vector_type(8)));
typedef float f32x4  __attribute__((ext_vector_type(4)));
typedef unsigned short u16x8 __attribute__((ext_vector_type(8)));

__device__ __forceinline__ unsigned bf16r(float f) {
    unsigned u = __float_as_uint(f);
    u += 0x7fffu + ((u >> 16) & 1u);   // round-to-nearest-even
    return u >> 16;
}
__device__ __forceinline__ unsigned pack_bf16(float lo, float hi) {
    return bf16r(lo) | (bf16r(hi) << 16);
}

// ---------------- cooperative prep: zero+convert -> deg -> scan -> fill ----------------
// Replaces memset + deg + scan1 + scan2 + scan3 + fill + conv (7 dispatches).
// Edge->partition mapping (blockIdx&7) is identical in P1 and P5 (same
// grid-stride structure) -- required for the privatized-counter CSR placement.
__global__ __launch_bounds__(256) void prep_kernel(
    const int* __restrict__ ei, int E, int N,
    int* __restrict__ deg8, int* __restrict__ fillc8, int* __restrict__ poff,
    int* __restrict__ row_ptr, int* __restrict__ bsum,
    float* __restrict__ dinv, unsigned* __restrict__ e_cw,
    const float2* __restrict__ x, unsigned* __restrict__ xb, int npk,
    const float* __restrict__ W1, const float* __restrict__ W2,
    const float* __restrict__ W3, unsigned short* __restrict__ Wt)
{
    cooperative_groups::grid_group grid = cooperative_groups::this_grid();
    const int t = threadIdx.x;
    const int gid = blockIdx.x * 256 + t;
    const int gstride = gridDim.x * 256;

    // P0: zero deg8+fillc8 (adjacent, 16N), convert x -> bf16x2, W -> Wt (transposed bf16)
    for (int i = gid; i < 16 * N; i += gstride) deg8[i] = 0;
    for (int i = gid; i < npk; i += gstride) {
        float2 v = x[i];
        xb[i] = pack_bf16(v.x, v.y);
    }
    const int PER = 3 * DFEAT * DFEAT;
    for (int i = gid; i < 3 * PER; i += gstride) {
        int layer = i / PER;
        int rem = i - layer * PER;
        const float* W = (layer == 0) ? W1 : ((layer == 1) ? W2 : W3);
        int seg = rem >> 14, k = (rem >> 7) & 127, nn = rem & 127;
        Wt[layer * PER + (seg << 14) + (nn << 7) + k] = (unsigned short)bf16r(W[rem]);
    }
    grid.sync();

    // P1: degree count (XCD-privatized partitions)
    for (int e = gid; e < E; e += gstride) {
        int r = ei[e];
        int c = ei[E + e];
        if (r != c) atomicAdd(&deg8[(blockIdx.x & 7) * N + r], 1);
    }
    grid.sync();

    // P2: per-node totals -> poff/dinv, 256-chunk-local inclusive scan -> row_ptr, bsum
    __shared__ int wsums[4];
    const int NCH = (N + 255) >> 8;
    for (int ch = blockIdx.x; ch < NCH; ch += gridDim.x) {
        int idx = ch * 256 + t;
        int tot = 0;
        if (idx < N) {
            int run = 0;
            #pragma unroll
            for (int p = 0; p < 8; ++p) {
                int d = deg8[p * N + idx];
                poff[p * N + idx] = run;
                run += d;
            }
            tot = run;
            dinv[idx] = (tot > 0) ? rsqrtf((float)tot) : 0.f;
        }
        int vi = tot;
        #pragma unroll
        for (int off = 1; off < 64; off <<= 1) {
            int xs = __shfl_up(vi, off);
            if ((t & 63) >= off) vi += xs;
        }
        if ((t & 63) == 63) wsums[t >> 6] = vi;
        __syncthreads();
        if (t < 4) {
            int s = wsums[t];
            int si = s;
            #pragma unroll
            for (int off = 1; off < 4; off <<= 1) {
                int xs = __shfl_up(si, off);
                if (t >= off) si += xs;
            }
            wsums[t] = si - s;                // exclusive prefix of wave sums
            if (t == 3) bsum[ch] = si;        // chunk total
        }
        __syncthreads();
        if (idx < N) row_ptr[idx + 1] = wsums[t >> 6] + vi;   // chunk-local inclusive
        __syncthreads();                      // before next chunk reuses wsums
    }
    grid.sync();

    // P3: exclusive scan of chunk sums (block 0, one wave)
    if (blockIdx.x == 0 && t < 64) {
        int carry = 0;
        for (int base = 0; base < NCH; base += 64) {
            int v = (base + t < NCH) ? bsum[base + t] : 0;
            int vi = v;
            #pragma unroll
            for (int off = 1; off < 64; off <<= 1) {
                int xs = __shfl_up(vi, off);
                if (t >= off) vi += xs;
            }
            if (base + t < NCH) bsum[base + t] = carry + vi - v;  // exclusive
            carry += __shfl(vi, 63);
        }
    }
    grid.sync();

    // P4: add chunk offsets
    if (gid == 0) row_ptr[0] = 0;
    for (int idx = gid; idx < N; idx += gstride)
        row_ptr[idx + 1] += bsum[idx >> 8];
    grid.sync();

    // P5: CSR fill, packed (col:u16 | w:f16)
    for (int e = gid; e < E; e += gstride) {
        int r = ei[e];
        int c = ei[E + e];
        if (r != c) {
            int p = blockIdx.x & 7;
            int k = atomicAdd(&fillc8[p * N + r], 1);
            int pos = row_ptr[r] + poff[p * N + r] + k;
            float w = -dinv[r] * dinv[c];
            _Float16 hf = (_Float16)w;
            unsigned short wb;
            __builtin_memcpy(&wb, &hf, 2);
            e_cw[pos] = (unsigned)c | ((unsigned)wb << 16);
        }
    }
}

// ---------------- sparse prop (bf16 in/out, fp32 accumulate) ----------------
// 1 wave per node (wave-uniform node -> scalar metadata loads); 16-wide
// load-then-FMA phases for 16 outstanding gathers per wave.
__global__ __launch_bounds__(256) void prop_bf16_kernel(
    const unsigned* __restrict__ hin, const unsigned* __restrict__ sub,
    unsigned* __restrict__ hout,
    const int* __restrict__ row_ptr, const unsigned* __restrict__ e_cw,
    float alpha, int n)
{
    int wv = __builtin_amdgcn_readfirstlane(threadIdx.x >> 6);
    int node = blockIdx.x * 4 + wv;
    int t = threadIdx.x & 63;     // feature pair: features 2t, 2t+1
    if (node >= n) return;
    int s = row_ptr[node];
    int e = row_ptr[node + 1];
    float a0 = 0.f, a1 = 0.f;
    int j = s;
    for (; j + 16 <= e; j += 16) {
        unsigned cw[16];
        #pragma unroll
        for (int q = 0; q < 16; ++q) cw[q] = e_cw[j + q];
        unsigned v[16];
        #pragma unroll
        for (int q = 0; q < 16; ++q)
            v[q] = hin[(size_t)(cw[q] & 0xffffu) * 64 + t];
        #pragma unroll
        for (int q = 0; q < 16; ++q) {
            unsigned short wb = (unsigned short)(cw[q] >> 16);
            _Float16 hf; __builtin_memcpy(&hf, &wb, 2);
            float w = (float)hf;
            a0 += w * __uint_as_float(v[q] << 16);
            a1 += w * __uint_as_float(v[q] & 0xffff0000u);
        }
    }
    for (; j + 4 <= e; j += 4) {
        unsigned cw[4];
        #pragma unroll
        for (int q = 0; q < 4; ++q) cw[q] = e_cw[j + q];
        unsigned v[4];
        #pragma unroll
        for (int q = 0; q < 4; ++q)
            v[q] = hin[(size_t)(cw[q] & 0xffffu) * 64 + t];
        #pragma unroll
        for (int q = 0; q < 4; ++q) {
            unsigned short wb = (unsigned short)(cw[q] >> 16);
            _Float16 hf; __builtin_memcpy(&hf, &wb, 2);
            float w = (float)hf;
            a0 += w * __uint_as_float(v[q] << 16);
            a1 += w * __uint_as_float(v[q] & 0xffff0000u);
        }
    }
    for (; j < e; ++j) {
        unsigned cwv = e_cw[j];
        unsigned short wb = (unsigned short)(cwv >> 16);
        _Float16 hf; __builtin_memcpy(&hf, &wb, 2);
        float w = (float)hf;
        unsigned v = hin[(size_t)(cwv & 0xffffu) * 64 + t];
        a0 += w * __uint_as_float(v << 16);
        a1 += w * __uint_as_float(v & 0xffff0000u);
    }
    a0 *= alpha; a1 *= alpha;
    if (sub) {
        unsigned v = sub[(size_t)node * 64 + t];
        a0 -= __uint_as_float(v << 16);
        a1 -= __uint_as_float(v & 0xffff0000u);
    }
    hout[(size_t)node * 64 + t] = pack_bf16(a0, a1);
}

// ---------------- fused 3-way MFMA GEMM + bias + ReLU ----------------
#define WPAD 136
__global__ __launch_bounds__(256) void gemm3_mfma_kernel(
    const unsigned short* __restrict__ X0, const unsigned short* __restrict__ X1,
    const unsigned short* __restrict__ X2,
    const unsigned short* __restrict__ Wt, const float* __restrict__ bias,
    void* __restrict__ out, int n, int out_bf16)
{
    __shared__ unsigned short Ws[DFEAT * WPAD];   // 34816 B
    const int t    = threadIdx.x;
    const int wave = t >> 6;
    const int lane = t & 63;
    const int quad = lane >> 4;
    const int l16  = lane & 15;

    const int row_base = blockIdx.x * 128 + wave * 32;
    int r0 = row_base + l16;       if (r0 >= n) r0 = n - 1;
    int r1 = row_base + 16 + l16;  if (r1 >= n) r1 = n - 1;

    const unsigned short* Xps[3] = {X0, X1, X2};

    f32x4 acc[2][8];
    #pragma unroll
    for (int tt = 0; tt < 2; ++tt)
        #pragma unroll
        for (int c = 0; c < 8; ++c) acc[tt][c] = (f32x4){0.f, 0.f, 0.f, 0.f};

    const int srow = t >> 1;            // staging: row 0..127
    const int shalf = (t & 1) * 64;     // half-row

    #pragma unroll
    for (int seg = 0; seg < 3; ++seg) {
        __syncthreads();   // previous seg fully consumed
        const unsigned short* Wp = Wt + (seg << 14);
        #pragma unroll
        for (int i = 0; i < 8; ++i) {
            *(u16x8*)&Ws[srow * WPAD + shalf + i * 8] =
                *(const u16x8*)&Wp[srow * DFEAT + shalf + i * 8];
        }
        __syncthreads();
        const unsigned short* A0 = Xps[seg] + (size_t)r0 * DFEAT;
        const unsigned short* A1 = Xps[seg] + (size_t)r1 * DFEAT;
        #pragma unroll
        for (int kk = 0; kk < 4; ++kk) {
            const int ko = kk * 32 + quad * 8;
            bf16x8 a0 = *(const bf16x8*)(A0 + ko);
            bf16x8 a1 = *(const bf16x8*)(A1 + ko);
            #pragma unroll
            for (int c = 0; c < 8; ++c) {
                bf16x8 b = *(const bf16x8*)&Ws[(c * 16 + l16) * WPAD + ko];
                acc[0][c] = __builtin_amdgcn_mfma_f32_16x16x32_bf16(a0, b, acc[0][c], 0, 0, 0);
                acc[1][c] = __builtin_amdgcn_mfma_f32_16x16x32_bf16(a1, b, acc[1][c], 0, 0, 0);
            }
        }
    }

    // C/D layout: col = lane&15, row = quad*4 + reg
    #pragma unroll
    for (int tt = 0; tt < 2; ++tt) {
        int orow0 = blockIdx.x * 128 + wave * 32 + tt * 16 + quad * 4;
        #pragma unroll
        for (int c = 0; c < 8; ++c) {
            int col = c * 16 + l16;
            float bv = bias[col];
            #pragma unroll
            for (int r = 0; r < 4; ++r) {
                int orow = orow0 + r;
                if (orow < n) {
                    float v = fmaxf(acc[tt][c][r] + bv, 0.f);
                    if (out_bf16)
                        ((unsigned short*)out)[(size_t)orow * DFEAT + col] = (unsigned short)bf16r(v);
                    else
                        ((float*)out)[(size_t)orow * DFEAT + col] = v;
                }
            }
        }
    }
}

extern "C" void kernel_launch(void* const* d_in, const int* in_sizes, int n_in,
                              void* d_out, int out_size, void* d_ws, size_t ws_size,
                              hipStream_t stream) {
    const float* x  = (const float*)d_in[0];
    const int*   ei = (const int*)d_in[1];
    const float* W1 = (const float*)d_in[2];
    const float* b1 = (const float*)d_in[3];
    const float* W2 = (const float*)d_in[4];
    const float* b2 = (const float*)d_in[5];
    const float* W3 = (const float*)d_in[6];
    const float* b3 = (const float*)d_in[7];

    const int N = in_sizes[0] / DFEAT;   // 50000
    const int E = in_sizes[1] / 2;       // 800000
    const int NPK = N * (DFEAT / 2);     // packed bf16x2 words per array
    const int NCH = (N + 255) / 256;     // scan chunks

    // workspace layout (deg8 and fillc8 adjacent -> one zero range)
    unsigned* xb  = (unsigned*)d_ws;
    unsigned* t1b = xb  + NPK;
    unsigned* t2b = t1b + NPK;
    unsigned* ab  = t2b + NPK;
    unsigned short* wt = (unsigned short*)(ab + NPK);   // 3 layers * 3*128*128
    int*   deg8    = (int*)(wt + 3 * 3 * DFEAT * DFEAT);
    int*   fillc8  = deg8 + 8 * N;
    int*   poff    = fillc8 + 8 * N;
    int*   row_ptr = poff + 8 * N;
    float* dinv    = (float*)(row_ptr + (N + 1));
    unsigned* e_cw = (unsigned*)(dinv + N);
    int*   bsum    = (int*)(e_cw + E);

    // single cooperative prep dispatch
    {
        const float2* x2 = (const float2*)x;
        const int* eip = ei;
        int Ev = E, Nv = N, npkv = NPK;
        void* args[] = {
            (void*)&eip, (void*)&Ev, (void*)&Nv,
            (void*)&deg8, (void*)&fillc8, (void*)&poff, (void*)&row_ptr, (void*)&bsum,
            (void*)&dinv, (void*)&e_cw,
            (void*)&x2, (void*)&xb, (void*)&npkv,
            (void*)&W1, (void*)&W2, (void*)&W3, (void*)&wt
        };
        hipLaunchCooperativeKernel((void*)prep_kernel, dim3(1024), dim3(256),
                                   args, 0, stream);
    }

    const float* bl[3] = {b1, b2, b3};
    const unsigned* hin = xb;
    const int prop_grid = (N + 3) / 4;
    const int gemm_grid = (N + 127) / 128;
    const int WELEM = 3 * DFEAT * DFEAT;
    for (int l = 0; l < 3; ++l) {
        // Tx1 = L_hat @ h
        prop_bf16_kernel<<<prop_grid, 256, 0, stream>>>(hin, nullptr, t1b, row_ptr, e_cw, 1.f, N);
        // Tx2 = 2 * L_hat @ Tx1 - h
        prop_bf16_kernel<<<prop_grid, 256, 0, stream>>>(t1b, hin, t2b, row_ptr, e_cw, 2.f, N);
        // out = relu(h@W0 + Tx1@W1 + Tx2@W2 + b)
        void* hout = (l == 2) ? d_out : (void*)ab;
        gemm3_mfma_kernel<<<gemm_grid, 256, 0, stream>>>(
            (const unsigned short*)hin, (const unsigned short*)t1b, (const unsigned short*)t2b,
            wt + l * WELEM, bl[l], hout, N, (l == 2) ? 0 : 1);
        hin = ab;
    }
}

// Round 8
// 402.075 us; speedup vs baseline: 2.2762x; 2.2762x over previous
//
#include <hip/hip_runtime.h>
#include <hip/hip_bf16.h>

#define DFEAT 128

typedef short bf16x8 __attribute__((ext_vector_type(8)));
typedef float f32x4  __attribute__((ext_vector_type(4)));
typedef unsigned short u16x8 __attribute__((ext_vector_type(8)));

__device__ __forceinline__ unsigned bf16r(float f) {
    unsigned u = __float_as_uint(f);
    u += 0x7fffu + ((u >> 16) & 1u);   // round-to-nearest-even
    return u >> 16;
}
__device__ __forceinline__ unsigned pack_bf16(float lo, float hi) {
    return bf16r(lo) | (bf16r(hi) << 16);
}
__device__ __forceinline__ float blo(unsigned v) { return __uint_as_float(v << 16); }
__device__ __forceinline__ float bhi(unsigned v) { return __uint_as_float(v & 0xffff0000u); }
__device__ __forceinline__ float f16w(unsigned cw) {
    unsigned short wb = (unsigned short)(cw >> 16);
    _Float16 hf; __builtin_memcpy(&hf, &wb, 2);
    return (float)hf;
}

// ---------------- degree count (XCD-privatized, fire-and-forget atomics) ----------------
__global__ void deg_kernel(const int* __restrict__ ei, int* __restrict__ deg8, int E, int N) {
    int e = blockIdx.x * blockDim.x + threadIdx.x;
    if (e < E) {
        int r = ei[e];
        int c = ei[E + e];
        if (r != c) atomicAdd(&deg8[(blockIdx.x & 7) * N + r], 1);
    }
}

// ---------------- scan stage 1 ----------------
__global__ __launch_bounds__(1024) void scan1_kernel(const int* __restrict__ deg8,
                                                     int* __restrict__ poff,
                                                     int* __restrict__ row_ptr,
                                                     int* __restrict__ bsum,
                                                     float* __restrict__ dinv, int n) {
    __shared__ int wsums[16];
    int t = threadIdx.x;
    int idx = blockIdx.x * 1024 + t;
    int tot = 0;
    if (idx < n) {
        int run = 0;
        #pragma unroll
        for (int p = 0; p < 8; ++p) {
            int d = deg8[p * n + idx];
            poff[p * n + idx] = run;
            run += d;
        }
        tot = run;
        dinv[idx] = (tot > 0) ? rsqrtf((float)tot) : 0.f;
    }
    int vi = tot;
    #pragma unroll
    for (int off = 1; off < 64; off <<= 1) {
        int x = __shfl_up(vi, off);
        if ((t & 63) >= off) vi += x;
    }
    if ((t & 63) == 63) wsums[t >> 6] = vi;
    __syncthreads();
    if (t < 16) {
        int s = wsums[t];
        int si = s;
        #pragma unroll
        for (int off = 1; off < 16; off <<= 1) {
            int x = __shfl_up(si, off);
            if (t >= off) si += x;
        }
        wsums[t] = si - s;
        if (t == 15) bsum[blockIdx.x] = si;
    }
    __syncthreads();
    if (idx < n) row_ptr[idx + 1] = wsums[t >> 6] + vi;
}

// ---------------- scan stage 2 ----------------
__global__ void scan2_kernel(int* __restrict__ bsum, int nb) {
    int t = threadIdx.x;   // 64 threads
    int carry = 0;
    for (int base = 0; base < nb; base += 64) {
        int v = (base + t < nb) ? bsum[base + t] : 0;
        int vi = v;
        #pragma unroll
        for (int off = 1; off < 64; off <<= 1) {
            int x = __shfl_up(vi, off);
            if (t >= off) vi += x;
        }
        if (base + t < nb) bsum[base + t] = carry + vi - v;
        carry += __shfl(vi, 63);
    }
}

// ---------------- scan stage 3 ----------------
__global__ __launch_bounds__(1024) void scan3_kernel(int* __restrict__ row_ptr,
                                                     const int* __restrict__ bsum, int n) {
    int idx = blockIdx.x * 1024 + threadIdx.x;
    if (idx == 0) row_ptr[0] = 0;
    if (idx < n) row_ptr[idx + 1] += bsum[blockIdx.x];
}

// ---------------- CSR fill: packed (col:u16 | w:f16) ----------------
__global__ void fill_kernel(const int* __restrict__ ei, const int* __restrict__ row_ptr,
                            const int* __restrict__ poff, int* __restrict__ fillc8,
                            const float* __restrict__ dinv,
                            unsigned* __restrict__ e_cw, int E, int N) {
    int e = blockIdx.x * blockDim.x + threadIdx.x;
    if (e < E) {
        int r = ei[e];
        int c = ei[E + e];
        if (r != c) {
            int p = blockIdx.x & 7;
            int k = atomicAdd(&fillc8[p * N + r], 1);
            int pos = row_ptr[r] + poff[p * N + r] + k;
            float w = -dinv[r] * dinv[c];
            _Float16 hf = (_Float16)w;
            unsigned short wb;
            __builtin_memcpy(&wb, &hf, 2);
            e_cw[pos] = (unsigned)c | ((unsigned)wb << 16);
        }
    }
}

// ---------------- fused convert: x->bf16 pack + W1/2/3 -> transposed bf16 ----------------
__global__ void conv_kernel(const float2* __restrict__ x, unsigned* __restrict__ xb, int npk,
                            const float* __restrict__ W1, const float* __restrict__ W2,
                            const float* __restrict__ W3, unsigned short* __restrict__ Wt) {
    int id = blockIdx.x * blockDim.x + threadIdx.x;
    if (id < npk) {
        float2 v = x[id];
        xb[id] = pack_bf16(v.x, v.y);
        return;
    }
    int id2 = id - npk;
    const int PER = 3 * DFEAT * DFEAT;
    if (id2 < 3 * PER) {
        int layer = id2 / PER;
        int rem = id2 - layer * PER;
        const float* W = (layer == 0) ? W1 : ((layer == 1) ? W2 : W3);
        int seg = rem >> 14;
        int k   = (rem >> 7) & 127;
        int nn  = rem & 127;
        Wt[layer * PER + (seg << 14) + (nn << 7) + k] = (unsigned short)bf16r(W[rem]);
    }
}

// ---------------- sparse prop v3 (bf16 in/out, fp32 accumulate) ----------------
// 1 wave per node; 2 edges processed per wave via half-wave split:
// lane = (h = lane>>5 edge parity, s = lane&31 8B row segment -> features 4s..4s+3).
// Metadata via wave-uniform scalar loads + per-lane cndmask select. 12-pair
// phases -> 12 uint2 gathers (6 KB) in flight per wave. Cross-half shfl_xor
// reduce; h==0 half stores uint2.
__global__ __launch_bounds__(256) void prop_bf16_kernel(
    const uint2* __restrict__ hin2, const uint2* __restrict__ sub2,
    uint2* __restrict__ hout2,
    const int* __restrict__ row_ptr, const unsigned* __restrict__ e_cw,
    float alpha, int n)
{
    int wv = __builtin_amdgcn_readfirstlane(threadIdx.x >> 6);
    int node = blockIdx.x * 4 + wv;
    if (node >= n) return;
    const int lane = threadIdx.x & 63;
    const int h = lane >> 5;       // edge parity within pair
    const int s = lane & 31;       // 8B segment (features 4s..4s+3)
    int rs = row_ptr[node];
    int re = row_ptr[node + 1];

    float a0 = 0.f, a1 = 0.f, a2 = 0.f, a3 = 0.f;

    for (int j = rs; j < re; j += 24) {
        uint2 vv[12]; float wv2[12];
        #pragma unroll
        for (int u = 0; u < 12; ++u) {
            int i0 = j + 2 * u;
            unsigned cw0 = (i0     < re) ? e_cw[i0]     : 0u;   // uniform -> s_load/s_cselect
            unsigned cw1 = (i0 + 1 < re) ? e_cw[i0 + 1] : 0u;
            unsigned cw = h ? cw1 : cw0;
            wv2[u] = f16w(cw);
            vv[u] = hin2[(size_t)(cw & 0xffffu) * 32 + s];
        }
        #pragma unroll
        for (int u = 0; u < 12; ++u) {
            float w = wv2[u];
            a0 += w * blo(vv[u].x);  a1 += w * bhi(vv[u].x);
            a2 += w * blo(vv[u].y);  a3 += w * bhi(vv[u].y);
        }
    }
    // combine the two halves (both hold the same features for this node)
    a0 += __shfl_xor(a0, 32);
    a1 += __shfl_xor(a1, 32);
    a2 += __shfl_xor(a2, 32);
    a3 += __shfl_xor(a3, 32);

    a0 *= alpha; a1 *= alpha; a2 *= alpha; a3 *= alpha;
    size_t rowoff = (size_t)node * 32 + s;
    if (sub2) {
        uint2 sv = sub2[rowoff];
        a0 -= blo(sv.x);  a1 -= bhi(sv.x);
        a2 -= blo(sv.y);  a3 -= bhi(sv.y);
    }
    if (h == 0) {
        uint2 o;
        o.x = pack_bf16(a0, a1);
        o.y = pack_bf16(a2, a3);
        hout2[rowoff] = o;
    }
}

// ---------------- fused 3-way MFMA GEMM + bias + ReLU ----------------
#define WPAD 136
__global__ __launch_bounds__(256) void gemm3_mfma_kernel(
    const unsigned short* __restrict__ X0, const unsigned short* __restrict__ X1,
    const unsigned short* __restrict__ X2,
    const unsigned short* __restrict__ Wt, const float* __restrict__ bias,
    void* __restrict__ out, int n, int out_bf16)
{
    __shared__ unsigned short Ws[DFEAT * WPAD];   // 34816 B
    const int t    = threadIdx.x;
    const int wave = t >> 6;
    const int lane = t & 63;
    const int quad = lane >> 4;
    const int l16  = lane & 15;

    const int row_base = blockIdx.x * 128 + wave * 32;
    int r0 = row_base + l16;       if (r0 >= n) r0 = n - 1;
    int r1 = row_base + 16 + l16;  if (r1 >= n) r1 = n - 1;

    const unsigned short* Xps[3] = {X0, X1, X2};

    f32x4 acc[2][8];
    #pragma unroll
    for (int tt = 0; tt < 2; ++tt)
        #pragma unroll
        for (int c = 0; c < 8; ++c) acc[tt][c] = (f32x4){0.f, 0.f, 0.f, 0.f};

    const int srow = t >> 1;            // staging: row 0..127
    const int shalf = (t & 1) * 64;     // half-row

    #pragma unroll
    for (int seg = 0; seg < 3; ++seg) {
        __syncthreads();   // previous seg fully consumed
        const unsigned short* Wp = Wt + (seg << 14);
        #pragma unroll
        for (int i = 0; i < 8; ++i) {
            *(u16x8*)&Ws[srow * WPAD + shalf + i * 8] =
                *(const u16x8*)&Wp[srow * DFEAT + shalf + i * 8];
        }
        __syncthreads();
        const unsigned short* A0 = Xps[seg] + (size_t)r0 * DFEAT;
        const unsigned short* A1 = Xps[seg] + (size_t)r1 * DFEAT;
        #pragma unroll
        for (int kk = 0; kk < 4; ++kk) {
            const int ko = kk * 32 + quad * 8;
            bf16x8 a0 = *(const bf16x8*)(A0 + ko);
            bf16x8 a1 = *(const bf16x8*)(A1 + ko);
            #pragma unroll
            for (int c = 0; c < 8; ++c) {
                bf16x8 b = *(const bf16x8*)&Ws[(c * 16 + l16) * WPAD + ko];
                acc[0][c] = __builtin_amdgcn_mfma_f32_16x16x32_bf16(a0, b, acc[0][c], 0, 0, 0);
                acc[1][c] = __builtin_amdgcn_mfma_f32_16x16x32_bf16(a1, b, acc[1][c], 0, 0, 0);
            }
        }
    }

    // C/D layout: col = lane&15, row = quad*4 + reg
    #pragma unroll
    for (int tt = 0; tt < 2; ++tt) {
        int orow0 = blockIdx.x * 128 + wave * 32 + tt * 16 + quad * 4;
        #pragma unroll
        for (int c = 0; c < 8; ++c) {
            int col = c * 16 + l16;
            float bv = bias[col];
            #pragma unroll
            for (int r = 0; r < 4; ++r) {
                int orow = orow0 + r;
                if (orow < n) {
                    float v = fmaxf(acc[tt][c][r] + bv, 0.f);
                    if (out_bf16)
                        ((unsigned short*)out)[(size_t)orow * DFEAT + col] = (unsigned short)bf16r(v);
                    else
                        ((float*)out)[(size_t)orow * DFEAT + col] = v;
                }
            }
        }
    }
}

extern "C" void kernel_launch(void* const* d_in, const int* in_sizes, int n_in,
                              void* d_out, int out_size, void* d_ws, size_t ws_size,
                              hipStream_t stream) {
    const float* x  = (const float*)d_in[0];
    const int*   ei = (const int*)d_in[1];
    const float* W1 = (const float*)d_in[2];
    const float* b1 = (const float*)d_in[3];
    const float* W2 = (const float*)d_in[4];
    const float* b2 = (const float*)d_in[5];
    const float* W3 = (const float*)d_in[6];
    const float* b3 = (const float*)d_in[7];

    const int N = in_sizes[0] / DFEAT;   // 50000
    const int E = in_sizes[1] / 2;       // 800000
    const int NPK = N * (DFEAT / 2);     // packed bf16x2 words per array
    const int NB = (N + 1023) / 1024;    // scan blocks

    // workspace layout (deg8 and fillc8 adjacent -> one memset)
    unsigned* xb  = (unsigned*)d_ws;
    unsigned* t1b = xb  + NPK;
    unsigned* t2b = t1b + NPK;
    unsigned* ab  = t2b + NPK;
    unsigned short* wt = (unsigned short*)(ab + NPK);   // 3 layers * 3*128*128
    int*   deg8    = (int*)(wt + 3 * 3 * DFEAT * DFEAT);
    int*   fillc8  = deg8 + 8 * N;
    int*   poff    = fillc8 + 8 * N;
    int*   row_ptr = poff + 8 * N;
    float* dinv    = (float*)(row_ptr + (N + 1));
    unsigned* e_cw = (unsigned*)(dinv + N);
    int*   bsum    = (int*)(e_cw + E);

    hipMemsetAsync(deg8, 0, sizeof(int) * 16 * N, stream);   // deg8 + fillc8

    deg_kernel<<<(E + 255) / 256, 256, 0, stream>>>(ei, deg8, E, N);
    scan1_kernel<<<NB, 1024, 0, stream>>>(deg8, poff, row_ptr, bsum, dinv, N);
    scan2_kernel<<<1, 64, 0, stream>>>(bsum, NB);
    scan3_kernel<<<NB, 1024, 0, stream>>>(row_ptr, bsum, N);
    fill_kernel<<<(E + 255) / 256, 256, 0, stream>>>(ei, row_ptr, poff, fillc8, dinv, e_cw, E, N);

    const int WELEM = 3 * DFEAT * DFEAT;
    const int CONVT = NPK + 3 * WELEM;
    conv_kernel<<<(CONVT + 255) / 256, 256, 0, stream>>>(
        (const float2*)x, xb, NPK, W1, W2, W3, wt);

    const float* bl[3] = {b1, b2, b3};
    const unsigned* hin = xb;
    const int prop_grid = (N + 3) / 4;
    const int gemm_grid = (N + 127) / 128;
    for (int l = 0; l < 3; ++l) {
        // Tx1 = L_hat @ h
        prop_bf16_kernel<<<prop_grid, 256, 0, stream>>>(
            (const uint2*)hin, nullptr, (uint2*)t1b, row_ptr, e_cw, 1.f, N);
        // Tx2 = 2 * L_hat @ Tx1 - h
        prop_bf16_kernel<<<prop_grid, 256, 0, stream>>>(
            (const uint2*)t1b, (const uint2*)hin, (uint2*)t2b, row_ptr, e_cw, 2.f, N);
        // out = relu(h@W0 + Tx1@W1 + Tx2@W2 + b)
        void* hout = (l == 2) ? d_out : (void*)ab;
        gemm3_mfma_kernel<<<gemm_grid, 256, 0, stream>>>(
            (const unsigned short*)hin, (const unsigned short*)t1b, (const unsigned short*)t2b,
            wt + l * WELEM, bl[l], hout, N, (l == 2) ? 0 : 1);
        hin = ab;
    }
}